// Round 8
// baseline (291.101 us; speedup 1.0000x reference)
//
#include <hip/hip_runtime.h>
#include <math.h>

#define EPS 1e-5f
#define SCALE 0.17677669529663687f   // 1/sqrt(32)

// packed bf16 weight offsets in d_ws (ushort units)
#define OFF_We  0
#define OFF_Wf  16384
#define OFF_Wq  24576
#define OFF_Wk  40960
#define OFF_Wv  57344
#define OFF_Wo  73728
#define OFF_Wc1 90112
#define PACK_TOTAL 98304

// fp32 param block appended after packed weights (float units, offset from ws+PACK_TOTAL)
#define P_BE   0
#define P_GE   128
#define P_BGE  256
#define P_BF   384
#define P_GF   512
#define P_BGF  640
#define P_BQ   768
#define P_BK   896
#define P_BV   1024
#define P_BO   1152
#define P_BC1  1280
#define P_GC   1344
#define P_BGC  1408
#define P_WC2  1472
#define P_MISC 1600
#define PARAM_N 1605

typedef __bf16 bf16x8 __attribute__((ext_vector_type(8)));
typedef float f32x4 __attribute__((ext_vector_type(4)));
typedef unsigned short ushort_t;
typedef unsigned short ushortx4 __attribute__((ext_vector_type(4)));

__device__ __forceinline__ ushort_t f2bf(float x) {
    unsigned u = __builtin_bit_cast(unsigned, x);
    u = (u + 0x7fffu + ((u >> 16) & 1u)) >> 16;   // RNE
    return (ushort_t)u;
}
__device__ __forceinline__ float bf2f(ushort_t v) {
    unsigned u = ((unsigned)v) << 16;
    return __builtin_bit_cast(float, u);
}

// 16-lane (DPP-row) all-lanes sum via row_ror butterfly — VALU pipe, no LDS.
#define DPPADD(x, ctrl) \
    ((x) + __builtin_bit_cast(float, __builtin_amdgcn_update_dpp( \
        __builtin_bit_cast(int, (x)), __builtin_bit_cast(int, (x)), (ctrl), 0xF, 0xF, false)))

__device__ __forceinline__ float rowsum16(float x) {
    x = DPPADD(x, 0x121);   // row_ror:1
    x = DPPADD(x, 0x122);   // row_ror:2
    x = DPPADD(x, 0x124);   // row_ror:4
    x = DPPADD(x, 0x128);   // row_ror:8
    return x;
}

// tanh-form GELU via sigmoid + HW exp; |err| <= ~4e-4 vs exact erf GELU
__device__ __forceinline__ float gelu_fast(float x) {
    float x2 = x * x;
    float u = x * fmaf(0.07135481283f, x2, 1.5957691216f);
    float e = __expf(-u);
    return x * __builtin_amdgcn_rcpf(1.0f + e);
}

// ---------------- pack kernel: bf16 B-fragment weights + fp32 param block ----------------
__global__ __launch_bounds__(256) void pack_all(
    const float* __restrict__ We, const float* __restrict__ Wf,
    const float* __restrict__ Wq, const float* __restrict__ Wk,
    const float* __restrict__ Wv, const float* __restrict__ Wo,
    const float* __restrict__ Wc1,
    const float* __restrict__ be, const float* __restrict__ ge, const float* __restrict__ bge,
    const float* __restrict__ bf, const float* __restrict__ gf, const float* __restrict__ bgf,
    const float* __restrict__ bq, const float* __restrict__ bk, const float* __restrict__ bv,
    const float* __restrict__ bo, const float* __restrict__ bc1, const float* __restrict__ gc,
    const float* __restrict__ bgc, const float* __restrict__ Wc2, const float* __restrict__ bc2,
    const float* __restrict__ fl, const float* __restrict__ temp,
    ushort_t* __restrict__ ws)
{
    int o = blockIdx.x * 256 + threadIdx.x;
    if (o < PACK_TOTAL) {
        const float* W; int K, N, base;
        if (o < OFF_Wf)        { W = We;  K = 128; N = 128; base = OFF_We; }
        else if (o < OFF_Wq)   { W = Wf;  K = 64;  N = 128; base = OFF_Wf; }
        else if (o < OFF_Wk)   { W = Wq;  K = 128; N = 128; base = OFF_Wq; }
        else if (o < OFF_Wv)   { W = Wk;  K = 128; N = 128; base = OFF_Wk; }
        else if (o < OFF_Wo)   { W = Wv;  K = 128; N = 128; base = OFF_Wv; }
        else if (o < OFF_Wc1)  { W = Wo;  K = 128; N = 128; base = OFF_Wo; }
        else                   { W = Wc1; K = 128; N = 64;  base = OFF_Wc1; }
        int e = o - base;
        int j = e & 7, l = (e >> 3) & 63, rest = e >> 9;
        int KS = K >> 5;
        int s = rest % KS, t = rest / KS;
        int k = s * 32 + ((l >> 4) << 3) + j;
        int n = (t << 4) + (l & 15);
        ws[o] = f2bf(W[k * N + n]);
        return;
    }
    int p = o - PACK_TOTAL;
    if (p >= PARAM_N) return;
    float* wsf = (float*)(ws + PACK_TOTAL);
    float v;
    if (p < 128)        v = be[p];
    else if (p < 256)   v = ge[p - 128];
    else if (p < 384)   v = bge[p - 256];
    else if (p < 512)   v = bf[p - 384];
    else if (p < 640)   v = gf[p - 512];
    else if (p < 768)   v = bgf[p - 640];
    else if (p < 896)   v = bq[p - 768];
    else if (p < 1024)  v = bk[p - 896];
    else if (p < 1152)  v = bv[p - 1024];
    else if (p < 1280)  v = bo[p - 1152];
    else if (p < 1344)  v = bc1[p - 1280];
    else if (p < 1408)  v = gc[p - 1344];
    else if (p < 1472)  v = bgc[p - 1408];
    else if (p < 1600)  v = Wc2[p - 1472];
    else if (p == 1600) v = bc2[0];
    else if (p == 1601) v = bc2[1];
    else if (p == 1602) v = fl[0];
    else if (p == 1603) v = fl[1];
    else                v = temp[0];
    wsf[p] = v;
}

// ---------------- weight prefetch (regs) + commit (LDS) ----------------
template<int NR>
__device__ __forceinline__ void pf_load(const ushort_t* __restrict__ ws, int offU,
                                        int tid, uint4* regs)
{
    const uint4* g = (const uint4*)(ws + offU);
    #pragma unroll
    for (int i = 0; i < NR; ++i) regs[i] = g[tid + i * 256];
}
template<int NR>
__device__ __forceinline__ void pf_commit(ushort_t* sW, int tid, const uint4* regs)
{
    __syncthreads();                       // all waves done reading previous sW
    uint4* d = (uint4*)sW;
    #pragma unroll
    for (int i = 0; i < NR; ++i) d[tid + i * 256] = regs[i];
    __syncthreads();                       // sW ready
}

// ---------------- GEMM helpers (A in regs, B from LDS sW, bias from LDS sP) ----------------
template<int KS>
__device__ __forceinline__ void load_af(bf16x8 af[KS], const ushort_t* A, int lane)
{
    const int quad = lane >> 4, l16 = lane & 15;
    #pragma unroll
    for (int ks = 0; ks < KS; ++ks)
        af[ks] = *(const bf16x8*)(A + l16 * 136 + ks * 32 + quad * 8);
}

template<int KS, int NTN>
__device__ __forceinline__ void mma_lds(const bf16x8 af[KS],
    const ushort_t* sW, const float* sB, int nt0, float acc[NTN][4], int lane)
{
    const int l16 = lane & 15;
    #pragma unroll
    for (int t = 0; t < NTN; ++t) {
        float b = sB[(nt0 + t) * 16 + l16];
        f32x4 a0 = {b, b, b, b};
        #pragma unroll
        for (int ks = 0; ks < KS; ++ks) {
            bf16x8 bb = *(const bf16x8*)(sW + (((nt0 + t) * KS + ks) * 64 + lane) * 8);
            a0 = __builtin_amdgcn_mfma_f32_16x16x32_bf16(af[ks], bb, a0, 0, 0, 0);
        }
        #pragma unroll
        for (int r = 0; r < 4; ++r) acc[t][r] = a0[r];
    }
}

// ---------------- main kernel: 4 waves x 16 wave-private rows, prefetched LDS weights ----------------
__global__ __launch_bounds__(256, 2) void fusion_stage(
    const float* __restrict__ eeg, const float* __restrict__ fmri,
    const ushort_t* __restrict__ ws, float* __restrict__ out)
{
    __shared__ __align__(16) ushort_t sW[16384];        // 32 KB weight stage buffer
    __shared__ __align__(16) float sP[1664];            // params
    __shared__ __align__(16) ushort_t B1[4][16 * 136];  // per-wave: eeg->ep->ctx->fused
    __shared__ __align__(16) ushort_t B2[4][16 * 136];  // per-wave: fmri->fp

    const int tid = threadIdx.x;
    const int wave = tid >> 6, lane = tid & 63;
    const int quad = lane >> 4, l16 = lane & 15;
    const int rowbase = blockIdx.x * 64 + wave * 16;
    ushort_t* b1 = B1[wave];
    ushort_t* b2 = B2[wave];

    uint4 pf[8];
    pf_load<8>(ws, OFF_We, tid, pf);       // We in flight under input staging

    // ---- params -> LDS (first use is after S1's commit barriers) ----
    {
        const float* src = (const float*)(ws + PACK_TOTAL);
        for (int i = tid; i < PARAM_N; i += 256) sP[i] = src[i];
    }

    // ---- stage raw inputs -> bf16 A-layout LDS (wave-private) ----
    {
        const float4* src = (const float4*)(eeg + (size_t)rowbase * 128);
        #pragma unroll
        for (int i = 0; i < 8; ++i) {
            int idx = i * 64 + lane;               // 512 float4 = 16 rows x 32
            float4 v = src[idx];
            int r = idx >> 5, k4 = (idx & 31) * 4;
            *(ushortx4*)&b1[r * 136 + k4] =
                (ushortx4){f2bf(v.x), f2bf(v.y), f2bf(v.z), f2bf(v.w)};
        }
        const float4* srcf = (const float4*)(fmri + (size_t)rowbase * 64);
        #pragma unroll
        for (int i = 0; i < 4; ++i) {
            int idx = i * 64 + lane;               // 256 float4 = 16 rows x 16
            float4 v = srcf[idx];
            int r = idx >> 4, k4 = (idx & 15) * 4;
            *(ushortx4*)&b2[r * 136 + k4] =
                (ushortx4){f2bf(v.x), f2bf(v.y), f2bf(v.z), f2bf(v.w)};
        }
    }

    float meanS[4], rstdS[4];

    // ---- S1: eeg @ We + be ; LN ; GELU -> ep (b1) ----
    pf_commit<8>(sW, tid, pf);
    pf_load<4>(ws, OFF_Wf, tid, pf);       // Wf in flight under S1
    {
        bf16x8 afR[4]; load_af<4>(afR, b1, lane);
        float acc[8][4];
        mma_lds<4, 8>(afR, sW, sP + P_BE, 0, acc, lane);
        #pragma unroll
        for (int r = 0; r < 4; ++r) {
            float s = 0.f, ss = 0.f;
            #pragma unroll
            for (int nt = 0; nt < 8; ++nt) { float x = acc[nt][r]; s += x; ss = fmaf(x, x, ss); }
            s = rowsum16(s); ss = rowsum16(ss);
            float m = s * (1.f / 128.f);
            meanS[r] = m;
            rstdS[r] = rsqrtf(ss * (1.f / 128.f) - m * m + EPS);
        }
        #pragma unroll
        for (int nt = 0; nt < 8; ++nt) {
            float g = sP[P_GE + nt * 16 + l16], bb = sP[P_BGE + nt * 16 + l16];
            #pragma unroll
            for (int r = 0; r < 4; ++r) {
                float x = (acc[nt][r] - meanS[r]) * rstdS[r] * g + bb;
                b1[(quad * 4 + r) * 136 + nt * 16 + l16] = f2bf(gelu_fast(x));
            }
        }
    }

    // ---- S2: fmri @ Wf + bf ; LN ; GELU -> fp (b2) ----
    pf_commit<4>(sW, tid, pf);
    pf_load<8>(ws, OFF_Wq, tid, pf);       // Wq in flight under S2
    {
        bf16x8 afR[2]; load_af<2>(afR, b2, lane);
        float acc[8][4];
        mma_lds<2, 8>(afR, sW, sP + P_BF, 0, acc, lane);
        #pragma unroll
        for (int r = 0; r < 4; ++r) {
            float s = 0.f, ss = 0.f;
            #pragma unroll
            for (int nt = 0; nt < 8; ++nt) { float x = acc[nt][r]; s += x; ss = fmaf(x, x, ss); }
            s = rowsum16(s); ss = rowsum16(ss);
            float m = s * (1.f / 128.f);
            meanS[r] = m;
            rstdS[r] = rsqrtf(ss * (1.f / 128.f) - m * m + EPS);
        }
        #pragma unroll
        for (int nt = 0; nt < 8; ++nt) {
            float g = sP[P_GF + nt * 16 + l16], bb = sP[P_BGF + nt * 16 + l16];
            #pragma unroll
            for (int r = 0; r < 4; ++r) {
                float x = (acc[nt][r] - meanS[r]) * rstdS[r] * g + bb;
                b2[(quad * 4 + r) * 136 + nt * 16 + l16] = f2bf(gelu_fast(x));
            }
        }
    }

    // persistent A-fragments for attention: ep (b1) and fp (b2)
    bf16x8 afE[4]; load_af<4>(afE, b1, lane);
    bf16x8 afF[4]; load_af<4>(afF, b2, lane);

    // ---- S3: q = ep @ Wq + bq (held in regs) ----
    pf_commit<8>(sW, tid, pf);
    pf_load<8>(ws, OFF_Wk, tid, pf);       // Wk in flight under S3
    float q[8][4];
    mma_lds<4, 8>(afE, sW, sP + P_BQ, 0, q, lane);

    // ---- S4: single Wk pass; accumulate score DIFFERENCE (softmax == sigmoid) ----
    pf_commit<8>(sW, tid, pf);
    pf_load<8>(ws, OFF_Wv, tid, pf);       // Wv in flight under S4
    float a0v[4][4];
    {
        float pd[4][4];
        #pragma unroll
        for (int h = 0; h < 4; ++h)
            #pragma unroll
            for (int r = 0; r < 4; ++r) pd[h][r] = 0.f;
        #pragma unroll
        for (int nt = 0; nt < 8; ++nt) {
            // bias cancels in the e-f difference; init 0
            f32x4 e = {0.f, 0.f, 0.f, 0.f}, f = {0.f, 0.f, 0.f, 0.f};
            #pragma unroll
            for (int ks = 0; ks < 4; ++ks) {
                bf16x8 bb = *(const bf16x8*)(sW + ((nt * 4 + ks) * 64 + lane) * 8);
                e = __builtin_amdgcn_mfma_f32_16x16x32_bf16(afE[ks], bb, e, 0, 0, 0);
                f = __builtin_amdgcn_mfma_f32_16x16x32_bf16(afF[ks], bb, f, 0, 0, 0);
            }
            int h = nt >> 1;
            #pragma unroll
            for (int r = 0; r < 4; ++r)
                pd[h][r] = fmaf(q[nt][r], e[r] - f[r], pd[h][r]);
        }
        #pragma unroll
        for (int h = 0; h < 4; ++h)
            #pragma unroll
            for (int r = 0; r < 4; ++r) {
                float d = rowsum16(pd[h][r]) * SCALE;   // s0 - s1
                a0v[h][r] = __builtin_amdgcn_rcpf(1.0f + __expf(-d));
            }
    }

    // ---- S5: ctx = a0*(ep@Wv) + (1-a0)*(fp@Wv) + bv -> b1 (bf16) ----
    pf_commit<8>(sW, tid, pf);
    pf_load<8>(ws, OFF_Wo, tid, pf);       // Wo in flight under S5
    #pragma unroll
    for (int nt = 0; nt < 8; ++nt) {
        float b = sP[P_BV + nt * 16 + l16];
        f32x4 e = {b, b, b, b}, f = {b, b, b, b};
        #pragma unroll
        for (int ks = 0; ks < 4; ++ks) {
            bf16x8 bb = *(const bf16x8*)(sW + ((nt * 4 + ks) * 64 + lane) * 8);
            e = __builtin_amdgcn_mfma_f32_16x16x32_bf16(afE[ks], bb, e, 0, 0, 0);
            f = __builtin_amdgcn_mfma_f32_16x16x32_bf16(afF[ks], bb, f, 0, 0, 0);
        }
        int h = nt >> 1;
        #pragma unroll
        for (int r = 0; r < 4; ++r) {
            float a0 = a0v[h][r];
            float c0 = a0 * e[r] + (1.0f - a0) * f[r];
            b1[(quad * 4 + r) * 136 + nt * 16 + l16] = f2bf(c0);
        }
    }

    // ---- S6: eeg_enh = ctx @ Wo + bo ; learned fusion with fp ; fused -> b1 ----
    pf_commit<8>(sW, tid, pf);
    pf_load<4>(ws, OFF_Wc1, tid, pf);      // Wc1 in flight under S6
    {
        bf16x8 afC[4]; load_af<4>(afC, b1, lane);
        float acc[8][4];
        mma_lds<4, 8>(afC, sW, sP + P_BO, 0, acc, lane);
        float t = sP[P_MISC + 4];
        float dl = (sP[P_MISC + 2] - sP[P_MISC + 3]) / t;
        float w0 = __builtin_amdgcn_rcpf(1.0f + __expf(-dl));
        float w1 = 1.0f - w0;
        #pragma unroll
        for (int nt = 0; nt < 8; ++nt)
            #pragma unroll
            for (int r = 0; r < 4; ++r) {
                int off = (quad * 4 + r) * 136 + nt * 16 + l16;
                float fp = bf2f(b2[off]);
                b1[off] = f2bf(w0 * acc[nt][r] + w1 * fp);
            }
    }

    // ---- S7: classifier: fused @ Wc1 + bc1 ; LN ; ReLU ; logits ----
    pf_commit<4>(sW, tid, pf);
    {
        bf16x8 afU[4]; load_af<4>(afU, b1, lane);
        float accH[4][4];
        mma_lds<4, 4>(afU, sW, sP + P_BC1, 0, accH, lane);
        #pragma unroll
        for (int r = 0; r < 4; ++r) {
            float s = 0.f, ss = 0.f;
            #pragma unroll
            for (int nt = 0; nt < 4; ++nt) { float x = accH[nt][r]; s += x; ss = fmaf(x, x, ss); }
            s = rowsum16(s); ss = rowsum16(ss);
            float m = s * (1.f / 64.f);
            meanS[r] = m;
            rstdS[r] = rsqrtf(ss * (1.f / 64.f) - m * m + EPS);
        }
        #pragma unroll
        for (int nt = 0; nt < 4; ++nt) {
            float g = sP[P_GC + nt * 16 + l16], bb = sP[P_BGC + nt * 16 + l16];
            #pragma unroll
            for (int r = 0; r < 4; ++r) {
                float x = (accH[nt][r] - meanS[r]) * rstdS[r] * g + bb;
                accH[nt][r] = fmaxf(x, 0.0f);
            }
        }
        float w2v[4][2];
        #pragma unroll
        for (int nt = 0; nt < 4; ++nt) {
            float2 w = *(const float2*)&sP[P_WC2 + (nt * 16 + l16) * 2];
            w2v[nt][0] = w.x; w2v[nt][1] = w.y;
        }
        float o0c = sP[P_MISC + 0], o1c = sP[P_MISC + 1];
        #pragma unroll
        for (int r = 0; r < 4; ++r) {
            float p0 = 0.f, p1 = 0.f;
            #pragma unroll
            for (int nt = 0; nt < 4; ++nt) {
                float hv = accH[nt][r];
                p0 = fmaf(hv, w2v[nt][0], p0);
                p1 = fmaf(hv, w2v[nt][1], p1);
            }
            p0 = rowsum16(p0); p1 = rowsum16(p1);
            if (l16 == 0) {
                int row = rowbase + quad * 4 + r;
                float2 o; o.x = p0 + o0c; o.y = p1 + o1c;
                *(float2*)&out[row * 2] = o;
            }
        }
    }
}

extern "C" void kernel_launch(void* const* d_in, const int* in_sizes, int n_in,
                              void* d_out, int out_size, void* d_ws, size_t ws_size,
                              hipStream_t stream) {
    const float* eeg  = (const float*)d_in[0];
    const float* fmri = (const float*)d_in[1];
    const float* We   = (const float*)d_in[2];
    const float* be   = (const float*)d_in[3];
    const float* ge   = (const float*)d_in[4];
    const float* bge  = (const float*)d_in[5];
    const float* Wf   = (const float*)d_in[6];
    const float* bf   = (const float*)d_in[7];
    const float* gf   = (const float*)d_in[8];
    const float* bgf  = (const float*)d_in[9];
    const float* Wq   = (const float*)d_in[10];
    const float* bq   = (const float*)d_in[11];
    const float* Wk   = (const float*)d_in[12];
    const float* bk   = (const float*)d_in[13];
    const float* Wv   = (const float*)d_in[14];
    const float* bv   = (const float*)d_in[15];
    const float* Wo   = (const float*)d_in[16];
    const float* bo   = (const float*)d_in[17];
    const float* fl   = (const float*)d_in[18];
    const float* temp = (const float*)d_in[19];
    const float* Wc1  = (const float*)d_in[20];
    const float* bc1  = (const float*)d_in[21];
    const float* gc   = (const float*)d_in[22];
    const float* bgc  = (const float*)d_in[23];
    const float* Wc2  = (const float*)d_in[24];
    const float* bc2  = (const float*)d_in[25];
    float* out = (float*)d_out;
    ushort_t* ws = (ushort_t*)d_ws;

    int packThreads = PACK_TOTAL + 2048;
    hipLaunchKernelGGL(pack_all, dim3((packThreads + 255) / 256), dim3(256), 0, stream,
                       We, Wf, Wq, Wk, Wv, Wo, Wc1,
                       be, ge, bge, bf, gf, bgf, bq, bk, bv, bo,
                       bc1, gc, bgc, Wc2, bc2, fl, temp, ws);

    int B = in_sizes[0] / 128;     // 131072
    int grid = B / 64;             // 2048 blocks x 256 threads (4 waves x 16 rows)
    hipLaunchKernelGGL(fusion_stage, dim3(grid), dim3(256), 0, stream,
                       eeg, fmri, ws, out);
}

// Round 9
// 213.824 us; speedup vs baseline: 1.3614x; 1.3614x over previous
//
#include <hip/hip_runtime.h>
#include <math.h>

#define EPS 1e-5f
#define SCALE 0.17677669529663687f   // 1/sqrt(32)

// packed bf16 weight offsets in d_ws (ushort units)
#define OFF_We  0
#define OFF_Wf  16384
#define OFF_Wq  24576
#define OFF_Wk  40960
#define OFF_Wv  57344
#define OFF_Wo  73728
#define OFF_Wc1 90112
#define PACK_TOTAL 98304

#define CHUNK 8192   // ushorts per stage chunk (16 KB = 4 n-tiles at KS=4)

typedef __bf16 bf16x8 __attribute__((ext_vector_type(8)));
typedef float f32x4 __attribute__((ext_vector_type(4)));
typedef unsigned short ushort_t;
typedef unsigned short ushortx4 __attribute__((ext_vector_type(4)));

__device__ __forceinline__ ushort_t f2bf(float x) {
    unsigned u = __builtin_bit_cast(unsigned, x);
    u = (u + 0x7fffu + ((u >> 16) & 1u)) >> 16;   // RNE
    return (ushort_t)u;
}
__device__ __forceinline__ float bf2f(ushort_t v) {
    unsigned u = ((unsigned)v) << 16;
    return __builtin_bit_cast(float, u);
}

// 16-lane (DPP-row) all-lanes sum via row_ror butterfly — VALU pipe, no LDS.
#define DPPADD(x, ctrl) \
    ((x) + __builtin_bit_cast(float, __builtin_amdgcn_update_dpp( \
        __builtin_bit_cast(int, (x)), __builtin_bit_cast(int, (x)), (ctrl), 0xF, 0xF, false)))

__device__ __forceinline__ float rowsum16(float x) {
    x = DPPADD(x, 0x121);   // row_ror:1
    x = DPPADD(x, 0x122);   // row_ror:2
    x = DPPADD(x, 0x124);   // row_ror:4
    x = DPPADD(x, 0x128);   // row_ror:8
    return x;
}

// tanh-form GELU via sigmoid + HW exp; |err| <= ~4e-4 vs exact erf GELU
__device__ __forceinline__ float gelu_fast(float x) {
    float x2 = x * x;
    float u = x * fmaf(0.07135481283f, x2, 1.5957691216f);
    float e = __expf(-u);
    return x * __builtin_amdgcn_rcpf(1.0f + e);
}

// ---------------- weight pack kernel (verified r2/r3/r5/r7) ----------------
__global__ __launch_bounds__(256) void pack_all(
    const float* __restrict__ We, const float* __restrict__ Wf,
    const float* __restrict__ Wq, const float* __restrict__ Wk,
    const float* __restrict__ Wv, const float* __restrict__ Wo,
    const float* __restrict__ Wc1, ushort_t* __restrict__ ws)
{
    int o = blockIdx.x * 256 + threadIdx.x;
    if (o >= PACK_TOTAL) return;
    const float* W; int K, N, base;
    if (o < OFF_Wf)        { W = We;  K = 128; N = 128; base = OFF_We; }
    else if (o < OFF_Wq)   { W = Wf;  K = 64;  N = 128; base = OFF_Wf; }
    else if (o < OFF_Wk)   { W = Wq;  K = 128; N = 128; base = OFF_Wq; }
    else if (o < OFF_Wv)   { W = Wk;  K = 128; N = 128; base = OFF_Wk; }
    else if (o < OFF_Wo)   { W = Wv;  K = 128; N = 128; base = OFF_Wv; }
    else if (o < OFF_Wc1)  { W = Wo;  K = 128; N = 128; base = OFF_Wo; }
    else                   { W = Wc1; K = 128; N = 64;  base = OFF_Wc1; }
    int e = o - base;
    int j = e & 7, l = (e >> 3) & 63, rest = e >> 9;
    int KS = K >> 5;
    int s = rest % KS, t = rest / KS;
    int k = s * 32 + ((l >> 4) << 3) + j;
    int n = (t << 4) + (l & 15);
    ws[o] = f2bf(W[k * N + n]);
}

// ---------------- GEMM helpers (A in regs, B from 16 KB LDS chunk) ----------------
template<int KS>
__device__ __forceinline__ void load_af(bf16x8 af[KS], const ushort_t* A, int lane)
{
    const int quad = lane >> 4, l16 = lane & 15;
    #pragma unroll
    for (int ks = 0; ks < KS; ++ks)
        af[ks] = *(const bf16x8*)(A + l16 * 136 + ks * 32 + quad * 8);
}

// chunk-local MFMA: sW holds NT4 n-tiles, accumulate into acc[0..NT4)
template<int KS, int NT4>
__device__ __forceinline__ void mma_c(const bf16x8 af[KS], const ushort_t* sW,
                                      f32x4* acc, int lane)
{
    #pragma unroll
    for (int t = 0; t < NT4; ++t)
        #pragma unroll
        for (int ks = 0; ks < KS; ++ks) {
            bf16x8 bb = *(const bf16x8*)(sW + ((t * KS + ks) * 64 + lane) * 8);
            acc[t] = __builtin_amdgcn_mfma_f32_16x16x32_bf16(af[ks], bb, acc[t], 0, 0, 0);
        }
}

// ---------------- main kernel: 4 waves x 16 wave-private rows, 16 KB chunked staging ----------------
__global__ __launch_bounds__(256, 3) void fusion_stage(
    const float* __restrict__ eeg, const float* __restrict__ fmri,
    const float* __restrict__ be, const float* __restrict__ ge, const float* __restrict__ bge,
    const float* __restrict__ bfb, const float* __restrict__ gf, const float* __restrict__ bgf,
    const float* __restrict__ bq, const float* __restrict__ bk, const float* __restrict__ bv,
    const float* __restrict__ bo,
    const float* __restrict__ fusion_logits, const float* __restrict__ temperature,
    const float* __restrict__ bc1, const float* __restrict__ gc, const float* __restrict__ bgc,
    const float* __restrict__ Wc2, const float* __restrict__ bc2,
    const ushort_t* __restrict__ ws, float* __restrict__ out)
{
    __shared__ __align__(16) ushort_t sW[CHUNK];        // 16 KB weight chunk buffer
    __shared__ __align__(16) ushort_t B1[4][16 * 136];  // per-wave: eeg->ep->ctx->fused
    __shared__ __align__(16) ushort_t B2[4][16 * 136];  // per-wave: fmri->fp

    const int tid = threadIdx.x;
    const int wave = tid >> 6, lane = tid & 63;
    const int quad = lane >> 4, l16 = lane & 15;
    const int rowbase = blockIdx.x * 64 + wave * 16;
    ushort_t* b1 = B1[wave];
    ushort_t* b2 = B2[wave];

    // cooperative chunk copy: barrier(prev consumed) ; copy 16 KB ; barrier(ready)
    auto stageW = [&](int offU) {
        __syncthreads();
        const uint4* g = (const uint4*)(ws + offU);
        uint4* d = (uint4*)sW;
        #pragma unroll
        for (int i = 0; i < 4; ++i) d[tid + i * 256] = g[tid + i * 256];
        __syncthreads();
    };

    // ---- stage raw inputs -> bf16 A-layout LDS (wave-private) ----
    {
        const float4* src = (const float4*)(eeg + (size_t)rowbase * 128);
        #pragma unroll
        for (int i = 0; i < 8; ++i) {
            int idx = i * 64 + lane;               // 512 float4 = 16 rows x 32
            float4 v = src[idx];
            int r = idx >> 5, k4 = (idx & 31) * 4;
            *(ushortx4*)&b1[r * 136 + k4] =
                (ushortx4){f2bf(v.x), f2bf(v.y), f2bf(v.z), f2bf(v.w)};
        }
        const float4* srcf = (const float4*)(fmri + (size_t)rowbase * 64);
        #pragma unroll
        for (int i = 0; i < 4; ++i) {
            int idx = i * 64 + lane;               // 256 float4 = 16 rows x 16
            float4 v = srcf[idx];
            int r = idx >> 4, k4 = (idx & 15) * 4;
            *(ushortx4*)&b2[r * 136 + k4] =
                (ushortx4){f2bf(v.x), f2bf(v.y), f2bf(v.z), f2bf(v.w)};
        }
    }

    float meanS[4], rstdS[4];

    // ---- S1: eeg @ We + be ; LN ; GELU -> ep (b1) ----
    {
        bf16x8 afR[4]; load_af<4>(afR, b1, lane);
        f32x4 acc[8];
        #pragma unroll
        for (int nt = 0; nt < 8; ++nt) {
            float b = be[nt * 16 + l16];
            acc[nt] = (f32x4){b, b, b, b};
        }
        stageW(OFF_We);          mma_c<4, 4>(afR, sW, acc + 0, lane);
        stageW(OFF_We + CHUNK);  mma_c<4, 4>(afR, sW, acc + 4, lane);
        #pragma unroll
        for (int r = 0; r < 4; ++r) {
            float s = 0.f, ss = 0.f;
            #pragma unroll
            for (int nt = 0; nt < 8; ++nt) { float x = acc[nt][r]; s += x; ss = fmaf(x, x, ss); }
            s = rowsum16(s); ss = rowsum16(ss);
            float m = s * (1.f / 128.f);
            meanS[r] = m;
            rstdS[r] = rsqrtf(ss * (1.f / 128.f) - m * m + EPS);
        }
        #pragma unroll
        for (int nt = 0; nt < 8; ++nt) {
            float g = ge[nt * 16 + l16], bb = bge[nt * 16 + l16];
            #pragma unroll
            for (int r = 0; r < 4; ++r) {
                float x = (acc[nt][r] - meanS[r]) * rstdS[r] * g + bb;
                b1[(quad * 4 + r) * 136 + nt * 16 + l16] = f2bf(gelu_fast(x));
            }
        }
    }

    // ---- S2: fmri @ Wf + bf ; LN ; GELU -> fp (b2)  (KS=2: all 8 tiles in one chunk) ----
    {
        bf16x8 afR[2]; load_af<2>(afR, b2, lane);
        f32x4 acc[8];
        #pragma unroll
        for (int nt = 0; nt < 8; ++nt) {
            float b = bfb[nt * 16 + l16];
            acc[nt] = (f32x4){b, b, b, b};
        }
        stageW(OFF_Wf);  mma_c<2, 8>(afR, sW, acc, lane);
        #pragma unroll
        for (int r = 0; r < 4; ++r) {
            float s = 0.f, ss = 0.f;
            #pragma unroll
            for (int nt = 0; nt < 8; ++nt) { float x = acc[nt][r]; s += x; ss = fmaf(x, x, ss); }
            s = rowsum16(s); ss = rowsum16(ss);
            float m = s * (1.f / 128.f);
            meanS[r] = m;
            rstdS[r] = rsqrtf(ss * (1.f / 128.f) - m * m + EPS);
        }
        #pragma unroll
        for (int nt = 0; nt < 8; ++nt) {
            float g = gf[nt * 16 + l16], bb = bgf[nt * 16 + l16];
            #pragma unroll
            for (int r = 0; r < 4; ++r) {
                float x = (acc[nt][r] - meanS[r]) * rstdS[r] * g + bb;
                b2[(quad * 4 + r) * 136 + nt * 16 + l16] = f2bf(gelu_fast(x));
            }
        }
    }

    // persistent A-fragments for attention: ep (b1) and fp (b2)
    bf16x8 afE[4]; load_af<4>(afE, b1, lane);
    bf16x8 afF[4]; load_af<4>(afF, b2, lane);

    // ---- S3: q = ep @ Wq + bq (held in regs) ----
    f32x4 q[8];
    {
        #pragma unroll
        for (int nt = 0; nt < 8; ++nt) {
            float b = bq[nt * 16 + l16];
            q[nt] = (f32x4){b, b, b, b};
        }
        stageW(OFF_Wq);          mma_c<4, 4>(afE, sW, q + 0, lane);
        stageW(OFF_Wq + CHUNK);  mma_c<4, 4>(afE, sW, q + 4, lane);
    }

    // ---- S4: single Wk pass; accumulate score DIFFERENCE (softmax == sigmoid) ----
    float a0v[4][4];
    {
        float pd[4][4];
        #pragma unroll
        for (int h = 0; h < 4; ++h)
            #pragma unroll
            for (int r = 0; r < 4; ++r) pd[h][r] = 0.f;
        #pragma unroll
        for (int c = 0; c < 2; ++c) {
            stageW(OFF_Wk + c * CHUNK);
            #pragma unroll
            for (int tl = 0; tl < 4; ++tl) {
                int nt = c * 4 + tl;
                f32x4 e = {0.f, 0.f, 0.f, 0.f}, f = {0.f, 0.f, 0.f, 0.f};
                #pragma unroll
                for (int ks = 0; ks < 4; ++ks) {
                    bf16x8 bb = *(const bf16x8*)(sW + ((tl * 4 + ks) * 64 + lane) * 8);
                    e = __builtin_amdgcn_mfma_f32_16x16x32_bf16(afE[ks], bb, e, 0, 0, 0);
                    f = __builtin_amdgcn_mfma_f32_16x16x32_bf16(afF[ks], bb, f, 0, 0, 0);
                }
                int h = nt >> 1;
                #pragma unroll
                for (int r = 0; r < 4; ++r)
                    pd[h][r] = fmaf(q[nt][r], e[r] - f[r], pd[h][r]);
            }
        }
        #pragma unroll
        for (int h = 0; h < 4; ++h)
            #pragma unroll
            for (int r = 0; r < 4; ++r) {
                float d = rowsum16(pd[h][r]) * SCALE;   // s0 - s1
                a0v[h][r] = __builtin_amdgcn_rcpf(1.0f + __expf(-d));
            }
    }

    // ---- S5: ctx = a0*(ep@Wv) + (1-a0)*(fp@Wv) + bv -> b1 (bf16) ----
    #pragma unroll
    for (int c = 0; c < 2; ++c) {
        stageW(OFF_Wv + c * CHUNK);
        #pragma unroll
        for (int tl = 0; tl < 4; ++tl) {
            int nt = c * 4 + tl;
            float b = bv[nt * 16 + l16];
            f32x4 e = {b, b, b, b}, f = {b, b, b, b};
            #pragma unroll
            for (int ks = 0; ks < 4; ++ks) {
                bf16x8 bb = *(const bf16x8*)(sW + ((tl * 4 + ks) * 64 + lane) * 8);
                e = __builtin_amdgcn_mfma_f32_16x16x32_bf16(afE[ks], bb, e, 0, 0, 0);
                f = __builtin_amdgcn_mfma_f32_16x16x32_bf16(afF[ks], bb, f, 0, 0, 0);
            }
            int h = nt >> 1;
            #pragma unroll
            for (int r = 0; r < 4; ++r) {
                float a0 = a0v[h][r];
                float c0 = a0 * e[r] + (1.0f - a0) * f[r];
                b1[(quad * 4 + r) * 136 + nt * 16 + l16] = f2bf(c0);
            }
        }
    }

    // ---- S6: eeg_enh = ctx @ Wo + bo ; learned fusion with fp ; fused -> b1 ----
    {
        bf16x8 afC[4]; load_af<4>(afC, b1, lane);
        f32x4 acc[8];
        #pragma unroll
        for (int nt = 0; nt < 8; ++nt) {
            float b = bo[nt * 16 + l16];
            acc[nt] = (f32x4){b, b, b, b};
        }
        stageW(OFF_Wo);          mma_c<4, 4>(afC, sW, acc + 0, lane);
        stageW(OFF_Wo + CHUNK);  mma_c<4, 4>(afC, sW, acc + 4, lane);
        float t = temperature[0];
        float dl = (fusion_logits[0] - fusion_logits[1]) / t;
        float w0 = __builtin_amdgcn_rcpf(1.0f + __expf(-dl));
        float w1 = 1.0f - w0;
        #pragma unroll
        for (int nt = 0; nt < 8; ++nt)
            #pragma unroll
            for (int r = 0; r < 4; ++r) {
                int off = (quad * 4 + r) * 136 + nt * 16 + l16;
                float fp = bf2f(b2[off]);
                b1[off] = f2bf(w0 * acc[nt][r] + w1 * fp);
            }
    }

    // ---- S7: classifier: fused @ Wc1 + bc1 ; LN ; ReLU ; logits ----
    {
        bf16x8 afU[4]; load_af<4>(afU, b1, lane);
        f32x4 accH[4];
        #pragma unroll
        for (int nt = 0; nt < 4; ++nt) {
            float b = bc1[nt * 16 + l16];
            accH[nt] = (f32x4){b, b, b, b};
        }
        stageW(OFF_Wc1);  mma_c<4, 4>(afU, sW, accH, lane);
        #pragma unroll
        for (int r = 0; r < 4; ++r) {
            float s = 0.f, ss = 0.f;
            #pragma unroll
            for (int nt = 0; nt < 4; ++nt) { float x = accH[nt][r]; s += x; ss = fmaf(x, x, ss); }
            s = rowsum16(s); ss = rowsum16(ss);
            float m = s * (1.f / 64.f);
            meanS[r] = m;
            rstdS[r] = rsqrtf(ss * (1.f / 64.f) - m * m + EPS);
        }
        float hv[4][4];
        #pragma unroll
        for (int nt = 0; nt < 4; ++nt) {
            float g = gc[nt * 16 + l16], bb = bgc[nt * 16 + l16];
            #pragma unroll
            for (int r = 0; r < 4; ++r) {
                float x = (accH[nt][r] - meanS[r]) * rstdS[r] * g + bb;
                hv[nt][r] = fmaxf(x, 0.0f);
            }
        }
        float w2v[4][2];
        #pragma unroll
        for (int nt = 0; nt < 4; ++nt) {
            float2 w = *(const float2*)&Wc2[(nt * 16 + l16) * 2];
            w2v[nt][0] = w.x; w2v[nt][1] = w.y;
        }
        float o0c = bc2[0], o1c = bc2[1];
        #pragma unroll
        for (int r = 0; r < 4; ++r) {
            float p0 = 0.f, p1 = 0.f;
            #pragma unroll
            for (int nt = 0; nt < 4; ++nt) {
                p0 = fmaf(hv[nt][r], w2v[nt][0], p0);
                p1 = fmaf(hv[nt][r], w2v[nt][1], p1);
            }
            p0 = rowsum16(p0); p1 = rowsum16(p1);
            if (l16 == 0) {
                int row = rowbase + quad * 4 + r;
                float2 o; o.x = p0 + o0c; o.y = p1 + o1c;
                *(float2*)&out[row * 2] = o;
            }
        }
    }
}

extern "C" void kernel_launch(void* const* d_in, const int* in_sizes, int n_in,
                              void* d_out, int out_size, void* d_ws, size_t ws_size,
                              hipStream_t stream) {
    const float* eeg  = (const float*)d_in[0];
    const float* fmri = (const float*)d_in[1];
    const float* We   = (const float*)d_in[2];
    const float* be   = (const float*)d_in[3];
    const float* ge   = (const float*)d_in[4];
    const float* bge  = (const float*)d_in[5];
    const float* Wf   = (const float*)d_in[6];
    const float* bf   = (const float*)d_in[7];
    const float* gf   = (const float*)d_in[8];
    const float* bgf  = (const float*)d_in[9];
    const float* Wq   = (const float*)d_in[10];
    const float* bq   = (const float*)d_in[11];
    const float* Wk   = (const float*)d_in[12];
    const float* bk   = (const float*)d_in[13];
    const float* Wv   = (const float*)d_in[14];
    const float* bv   = (const float*)d_in[15];
    const float* Wo   = (const float*)d_in[16];
    const float* bo   = (const float*)d_in[17];
    const float* fl   = (const float*)d_in[18];
    const float* temp = (const float*)d_in[19];
    const float* Wc1  = (const float*)d_in[20];
    const float* bc1  = (const float*)d_in[21];
    const float* gc   = (const float*)d_in[22];
    const float* bgc  = (const float*)d_in[23];
    const float* Wc2  = (const float*)d_in[24];
    const float* bc2  = (const float*)d_in[25];
    float* out = (float*)d_out;
    ushort_t* ws = (ushort_t*)d_ws;

    hipLaunchKernelGGL(pack_all, dim3((PACK_TOTAL + 255) / 256), dim3(256), 0, stream,
                       We, Wf, Wq, Wk, Wv, Wo, Wc1, ws);

    int B = in_sizes[0] / 128;     // 131072
    int grid = B / 64;             // 2048 blocks x 256 threads (4 waves x 16 rows)
    hipLaunchKernelGGL(fusion_stage, dim3(grid), dim3(256), 0, stream,
                       eeg, fmri, be, ge, bge, bf, gf, bgf,
                       bq, bk, bv, bo, fl, temp, bc1, gc, bgc, Wc2, bc2,
                       ws, out);
}